// Round 1
// baseline (518.950 us; speedup 1.0000x reference)
//
#include <hip/hip_runtime.h>

typedef unsigned short u16;
typedef short bf16x8 __attribute__((ext_vector_type(8)));
typedef float f32x4 __attribute__((ext_vector_type(4)));
typedef u16 u16x4 __attribute__((ext_vector_type(4)));

#define SCALE_Q 0.044194173824159216f   // 1/sqrt(512)

__device__ __forceinline__ u16 f2b(float f){   // fp32 -> bf16 RNE
  unsigned u = __float_as_uint(f);
  u += 0x7fffu + ((u >> 16) & 1u);
  return (u16)(u >> 16);
}

__device__ __forceinline__ void gload16(const void* g, void* l){
  __builtin_amdgcn_global_load_lds(
      (const __attribute__((address_space(1))) void*)g,
      (__attribute__((address_space(3))) void*)l, 16, 0, 0);
}

// ---------------- GroupNorm stats: one block per (b, group) ----------------
__global__ __launch_bounds__(256) void gn_stats(const float* __restrict__ x,
                                                float* __restrict__ stats){
  int bg = blockIdx.x;                       // 0..127
  const float4* p4 = (const float4*)(x + (size_t)bg * 65536);
  float s = 0.f, ss = 0.f;
  for (int i = threadIdx.x; i < 16384; i += 256){
    float4 v = p4[i];
    s  += v.x + v.y + v.z + v.w;
    ss += v.x*v.x + v.y*v.y + v.z*v.z + v.w*v.w;
  }
  for (int off = 32; off; off >>= 1){
    s  += __shfl_down(s, off);
    ss += __shfl_down(ss, off);
  }
  __shared__ float as_[4], bs_[4];
  int wid = threadIdx.x >> 6, lid = threadIdx.x & 63;
  if (lid == 0){ as_[wid] = s; bs_[wid] = ss; }
  __syncthreads();
  if (threadIdx.x == 0){
    float S = as_[0]+as_[1]+as_[2]+as_[3], SS = bs_[0]+bs_[1]+bs_[2]+bs_[3];
    float mean = S * (1.f/65536.f);
    float var  = SS * (1.f/65536.f) - mean*mean;
    stats[2*bg]   = mean;
    stats[2*bg+1] = rsqrtf(var + 1e-6f);
  }
}

// ------- normalize + affine + transpose [b,c,N] -> t[b,N,c] (bf16) ---------
__global__ __launch_bounds__(256) void gn_apply_T(const float* __restrict__ x,
                                                  const float* __restrict__ stats,
                                                  const float* __restrict__ gamma,
                                                  const float* __restrict__ beta,
                                                  u16* __restrict__ t){
  __shared__ float tile[32][33];
  int nb = blockIdx.x, cb = blockIdx.y, b = blockIdx.z;
  int tx = threadIdx.x & 31, ty = threadIdx.x >> 5;
  int n0 = nb * 32, c0 = cb * 32;
  #pragma unroll
  for (int i = 0; i < 4; i++){
    int ch = c0 + ty + i*8;
    float mean = stats[2*((b<<5) + (ch>>4))];
    float rstd = stats[2*((b<<5) + (ch>>4)) + 1];
    float v = x[(((size_t)b*512 + ch) << 12) + n0 + tx];
    tile[ty + i*8][tx] = (v - mean) * rstd * gamma[ch] + beta[ch];
  }
  __syncthreads();
  #pragma unroll
  for (int i = 0; i < 4; i++){
    int n = n0 + ty + i*8;
    int ch = c0 + tx;
    t[((size_t)((b<<12) + n))*512 + ch] = f2b(tile[tx][ty + i*8]);
  }
}

// ---------------- fp32 -> bf16 weight conversion (4 matrices) --------------
__global__ __launch_bounds__(256) void w2bf(const float* __restrict__ a,
                                            const float* __restrict__ b,
                                            const float* __restrict__ c,
                                            const float* __restrict__ d,
                                            u16* __restrict__ o){
  int idx = blockIdx.x * 256 + threadIdx.x;         // 0..262143 float4 units
  int which = idx >> 16;
  const float4* src = (const float4*)(which == 0 ? a : which == 1 ? b : which == 2 ? c : d);
  float4 v = src[idx & 65535];
  u16x4 pk;
  pk.x = f2b(v.x); pk.y = f2b(v.y); pk.z = f2b(v.z); pk.w = f2b(v.w);
  *(u16x4*)(o + (size_t)idx*4) = pk;
}

// ------------- gemm_bt: C[m][n] = A[m][:]·Bw[n][:] + bias[n] ---------------
// A bf16 [16384,512] row-major, Bw bf16 [512,512] row-major (already B^T form)
// variant 0: bf16 out[m][n], value=(acc+bias)*oscale
// variant 1: bf16 out transposed [b][n][tok] (for V)
// variant 2: fp32 out transposed + residual (final output)
__global__ __launch_bounds__(256, 2) void gemm_bt(const u16* __restrict__ A,
                                                  const u16* __restrict__ Bw,
                                                  const float* __restrict__ bias,
                                                  void* __restrict__ outp,
                                                  const float* __restrict__ resid,
                                                  float oscale, int variant){
  __shared__ __align__(16) u16 As[128*32];
  __shared__ __align__(16) u16 Bs[128*32];
  const int t = threadIdx.x;
  const int w = t >> 6, ln = t & 63;
  const int wr = w >> 1, wc = w & 1;
  const int q4 = ln >> 4, l15 = ln & 15;
  const u16* Ab = A  + (size_t)blockIdx.x * 128 * 512;
  const u16* Bb = Bw + (size_t)blockIdx.y * 128 * 512;
  f32x4 acc[4][4];
  #pragma unroll
  for (int i = 0; i < 4; i++)
    #pragma unroll
    for (int j = 0; j < 4; j++){
      acc[i][j][0]=0.f; acc[i][j][1]=0.f; acc[i][j][2]=0.f; acc[i][j][3]=0.f;
    }

  for (int kt = 0; kt < 16; ++kt){
    #pragma unroll
    for (int i = 0; i < 2; i++){
      int idx = i*256 + t;                       // 0..511
      gload16(Ab + (size_t)(idx>>2)*512 + kt*32 + (idx&3)*8, As + (size_t)idx*8);
      gload16(Bb + (size_t)(idx>>2)*512 + kt*32 + (idx&3)*8, Bs + (size_t)idx*8);
    }
    __syncthreads();
    bf16x8 af[4], bf[4];
    #pragma unroll
    for (int mt = 0; mt < 4; mt++)
      af[mt] = *(const bf16x8*)(As + (wr*64 + mt*16 + l15)*32 + q4*8);
    #pragma unroll
    for (int nt = 0; nt < 4; nt++)
      bf[nt] = *(const bf16x8*)(Bs + (wc*64 + nt*16 + l15)*32 + q4*8);
    #pragma unroll
    for (int mt = 0; mt < 4; mt++)
      #pragma unroll
      for (int nt = 0; nt < 4; nt++)
        acc[mt][nt] = __builtin_amdgcn_mfma_f32_16x16x32_bf16(af[mt], bf[nt], acc[mt][nt], 0, 0, 0);
    __syncthreads();
  }

  const int row0 = blockIdx.x*128 + wr*64;
  const int col0 = blockIdx.y*128 + wc*64;
  if (variant == 0){
    u16* out = (u16*)outp;
    #pragma unroll
    for (int nt = 0; nt < 4; nt++){
      int n = col0 + nt*16 + l15;
      float bv = bias[n];
      #pragma unroll
      for (int mt = 0; mt < 4; mt++){
        int m0 = row0 + mt*16 + q4*4;
        #pragma unroll
        for (int r = 0; r < 4; r++)
          out[(size_t)(m0 + r)*512 + n] = f2b((acc[mt][nt][r] + bv) * oscale);
      }
    }
  } else if (variant == 1){
    u16* out = (u16*)outp;
    #pragma unroll
    for (int nt = 0; nt < 4; nt++){
      int n = col0 + nt*16 + l15;
      float bv = bias[n];
      #pragma unroll
      for (int mt = 0; mt < 4; mt++){
        int m0 = row0 + mt*16 + q4*4;
        int bb = m0 >> 12, tok = m0 & 4095;
        u16x4 pk;
        pk.x = f2b(acc[mt][nt][0] + bv);
        pk.y = f2b(acc[mt][nt][1] + bv);
        pk.z = f2b(acc[mt][nt][2] + bv);
        pk.w = f2b(acc[mt][nt][3] + bv);
        *(u16x4*)(out + (((size_t)(bb*512 + n)) << 12) + tok) = pk;
      }
    }
  } else {
    float* out = (float*)outp;
    #pragma unroll
    for (int nt = 0; nt < 4; nt++){
      int n = col0 + nt*16 + l15;
      float bv = bias[n];
      #pragma unroll
      for (int mt = 0; mt < 4; mt++){
        int m0 = row0 + mt*16 + q4*4;
        int bb = m0 >> 12, tok = m0 & 4095;
        size_t base = (((size_t)(bb*512 + n)) << 12) + tok;
        float4 xr = *(const float4*)(resid + base);
        float4 ov;
        ov.x = acc[mt][nt][0] + bv + xr.x;
        ov.y = acc[mt][nt][1] + bv + xr.y;
        ov.z = acc[mt][nt][2] + bv + xr.z;
        ov.w = acc[mt][nt][3] + bv + xr.w;
        *(float4*)(out + base) = ov;
      }
    }
  }
}

// --------- flash attention: q[b,N,512](pre-scaled), k[b,N,512], vT[b,512,N] -
// out O bf16 [b,N,512]. BM=32 q rows per block, BN=32 k rows per iter.
__global__ __launch_bounds__(256, 2) void attn_fwd(const u16* __restrict__ q,
                                                   const u16* __restrict__ k,
                                                   const u16* __restrict__ vT,
                                                   u16* __restrict__ outO){
  // Kt layout [ks(16)][row(32)][kc(32)] -> 64B rows (bank-friendly, m97-style)
  __shared__ __align__(16) u16 Kt[16*32*32];
  __shared__ __align__(16) u16 Vt[512*32];       // [c][kr], 64B rows
  __shared__ __align__(16) float Sb[32*32];
  __shared__ __align__(16) u16 Pb[32*32];
  __shared__ __align__(16) float mS[32];
  __shared__ __align__(16) float lS[32];
  __shared__ __align__(16) float aS[32];
  const int t = threadIdx.x, w = t >> 6, ln = t & 63;
  const int q4 = ln >> 4, l15 = ln & 15;
  const int b = blockIdx.y;
  const int q0 = blockIdx.x * 32;
  const u16* qb = q  + ((size_t)b << 21);
  const u16* kb = k  + ((size_t)b << 21);
  const u16* vb = vT + ((size_t)b << 21);

  bf16x8 qf[16];
  {
    const u16* qrow = qb + (size_t)(q0 + 16*(w>>1) + l15) * 512;
    #pragma unroll
    for (int ks = 0; ks < 16; ks++)
      qf[ks] = *(const bf16x8*)(qrow + ks*32 + q4*8);
  }
  f32x4 oacc[2][8];
  #pragma unroll
  for (int i = 0; i < 2; i++)
    #pragma unroll
    for (int j = 0; j < 8; j++){
      oacc[i][j][0]=0.f; oacc[i][j][1]=0.f; oacc[i][j][2]=0.f; oacc[i][j][3]=0.f;
    }
  if (t < 32){ mS[t] = -1e30f; lS[t] = 0.f; }

  for (int j = 0; j < 128; j++){
    const int k0 = j * 32;
    #pragma unroll
    for (int i = 0; i < 8; i++){                 // K tile: 32KB
      int ci = i*256 + t;                        // 16B-chunk index 0..2047
      int ks = ci >> 7, row = (ci >> 2) & 31, c4 = ci & 3;
      gload16(kb + (size_t)(k0 + row)*512 + ks*32 + c4*8, Kt + (size_t)ci*8);
    }
    #pragma unroll
    for (int i = 0; i < 8; i++){                 // V^T tile: 32KB
      int ci = i*256 + t;
      gload16(vb + (size_t)(ci>>2)*4096 + k0 + (ci&3)*8, Vt + (size_t)ci*8);
    }
    __syncthreads();
    // phase 1: S = Q K^T (already scaled via q)
    {
      const int sr = 16*(w>>1), sc = 16*(w&1);
      f32x4 s; s[0]=0.f; s[1]=0.f; s[2]=0.f; s[3]=0.f;
      #pragma unroll
      for (int ks = 0; ks < 16; ks++){
        bf16x8 kf = *(const bf16x8*)(Kt + (ks*32 + sc + l15)*32 + q4*8);
        s = __builtin_amdgcn_mfma_f32_16x16x32_bf16(qf[ks], kf, s, 0, 0, 0);
      }
      #pragma unroll
      for (int r = 0; r < 4; r++)
        Sb[(sr + q4*4 + r)*32 + sc + l15] = s[r];
    }
    __syncthreads();
    // phase 2: online softmax (8 threads per row, 4 cols each)
    {
      const int r = t >> 3, part = t & 7;
      float4 sv = *(const float4*)(Sb + r*32 + part*4);
      float mx = fmaxf(fmaxf(sv.x, sv.y), fmaxf(sv.z, sv.w));
      mx = fmaxf(mx, __shfl_xor(mx, 1));
      mx = fmaxf(mx, __shfl_xor(mx, 2));
      mx = fmaxf(mx, __shfl_xor(mx, 4));
      float mold = mS[r];
      float mnew = fmaxf(mold, mx);
      float e0 = __expf(sv.x - mnew), e1 = __expf(sv.y - mnew);
      float e2 = __expf(sv.z - mnew), e3 = __expf(sv.w - mnew);
      float ps = e0 + e1 + e2 + e3;
      ps += __shfl_xor(ps, 1);
      ps += __shfl_xor(ps, 2);
      ps += __shfl_xor(ps, 4);
      if (part == 0){
        float alpha = __expf(mold - mnew);
        aS[r] = alpha;
        mS[r] = mnew;
        lS[r] = lS[r]*alpha + ps;
      }
      u16x4 pk; pk.x = f2b(e0); pk.y = f2b(e1); pk.z = f2b(e2); pk.w = f2b(e3);
      *(u16x4*)(Pb + r*32 + part*4) = pk;
    }
    __syncthreads();
    // phase 3: O = O*alpha + P V   (wave w owns cols [128w,128w+128))
    {
      bf16x8 vf[8];
      #pragma unroll
      for (int ct = 0; ct < 8; ct++)
        vf[ct] = *(const bf16x8*)(Vt + (w*128 + ct*16 + l15)*32 + q4*8);
      #pragma unroll
      for (int rt = 0; rt < 2; rt++){
        const float4 al = *(const float4*)(aS + rt*16 + q4*4);
        bf16x8 pf = *(const bf16x8*)(Pb + (rt*16 + l15)*32 + q4*8);
        #pragma unroll
        for (int ct = 0; ct < 8; ct++){
          f32x4 a = oacc[rt][ct];
          a[0] *= al.x; a[1] *= al.y; a[2] *= al.z; a[3] *= al.w;
          oacc[rt][ct] = __builtin_amdgcn_mfma_f32_16x16x32_bf16(pf, vf[ct], a, 0, 0, 0);
        }
      }
    }
    __syncthreads();
  }
  // epilogue: O /= l, write bf16 [b][tok][c]
  #pragma unroll
  for (int rt = 0; rt < 2; rt++){
    const float4 lv = *(const float4*)(lS + rt*16 + q4*4);
    float i0 = 1.f/lv.x, i1 = 1.f/lv.y, i2 = 1.f/lv.z, i3 = 1.f/lv.w;
    #pragma unroll
    for (int ct = 0; ct < 8; ct++){
      int col = w*128 + ct*16 + l15;
      u16* op = outO + ((size_t)((b<<12) + q0 + rt*16 + q4*4))*512 + col;
      op[0]    = f2b(oacc[rt][ct][0]*i0);
      op[512]  = f2b(oacc[rt][ct][1]*i1);
      op[1024] = f2b(oacc[rt][ct][2]*i2);
      op[1536] = f2b(oacc[rt][ct][3]*i3);
    }
  }
}

extern "C" void kernel_launch(void* const* d_in, const int* in_sizes, int n_in,
                              void* d_out, int out_size, void* d_ws, size_t ws_size,
                              hipStream_t stream){
  const float* x     = (const float*)d_in[0];
  const float* gamma = (const float*)d_in[1];
  const float* beta  = (const float*)d_in[2];
  const float* wq_w  = (const float*)d_in[3];
  const float* wq_b  = (const float*)d_in[4];
  const float* wk_w  = (const float*)d_in[5];
  const float* wk_b  = (const float*)d_in[6];
  const float* wv_w  = (const float*)d_in[7];
  const float* wv_b  = (const float*)d_in[8];
  const float* out_w = (const float*)d_in[9];
  const float* out_b = (const float*)d_in[10];

  char* ws = (char*)d_ws;
  float* stats = (float*)ws;                                   // 1 KB
  u16* tbuf = (u16*)(ws + 4096);                               // 16 MB (reused as O)
  size_t off = 4096 + (size_t)16*1024*1024;
  u16* Wcat = (u16*)(ws + off); off += (size_t)4*512*512*2;    // 2 MB
  u16* qb   = (u16*)(ws + off); off += (size_t)16*1024*1024;
  u16* kb   = (u16*)(ws + off); off += (size_t)16*1024*1024;
  u16* vTb  = (u16*)(ws + off); off += (size_t)16*1024*1024;   // ~67 MB total

  gn_stats<<<128, 256, 0, stream>>>(x, stats);
  gn_apply_T<<<dim3(128, 16, 4), 256, 0, stream>>>(x, stats, gamma, beta, tbuf);
  w2bf<<<1024, 256, 0, stream>>>(wq_w, wk_w, wv_w, out_w, Wcat);
  u16* Wq = Wcat;
  u16* Wk = Wcat + 512*512;
  u16* Wv = Wcat + 2*512*512;
  u16* Wo = Wcat + 3*512*512;
  gemm_bt<<<dim3(128, 4), 256, 0, stream>>>(tbuf, Wq, wq_b, qb,  nullptr, SCALE_Q, 0);
  gemm_bt<<<dim3(128, 4), 256, 0, stream>>>(tbuf, Wk, wk_b, kb,  nullptr, 1.f, 0);
  gemm_bt<<<dim3(128, 4), 256, 0, stream>>>(tbuf, Wv, wv_b, vTb, nullptr, 1.f, 1);
  attn_fwd<<<dim3(128, 4), 256, 0, stream>>>(qb, kb, vTb, tbuf);   // O overwrites t
  gemm_bt<<<dim3(128, 4), 256, 0, stream>>>(tbuf, Wo, out_b, d_out, x, 1.f, 2);
}